// Round 5
// baseline (16836.655 us; speedup 1.0000x reference)
//
#include <hip/hip_runtime.h>

// ---------------------------------------------------------------------------
// BiGCN-style forward: 2x GCNConv + root-extend + mean-pool + FC
// N=100000 nodes, E=1e6 edges, 128 feats, 512 graphs.
//
// Accuracy-first decomposition (all long accumulations in fp64 registers):
//   deg[i]    = in-degree(i)                       (int atomics, exact)
//   dinv      = (float)(1/sqrt(deg+1))             (exact to fp32)
//   CSR by dst: rowptr (scan of deg), csr_src, csr_w = dinv[s]*dinv[d]
//   h1        = x @ W1                             (fp32 in, fp64 acc GEMM)
//   nrep[d]   = b1 + h1[d]*dinv^2 + sum_in h1[s]*w (fp64 gather per node)
//   rootW2[g] = relu(x[root_g]) @ W2[128:]         (fp64 acc)
//   h2        = relu(nrep) @ W2[:128] + rootW2[batch]  (fp64 acc GEMM)
//   Xf[:,:128]  = relu(b2 + gather(h2))            (fp64 gather, relu in finalize)
//   Xf[:,128:]  = nrep[root(batch)]
//   out       = mean-pool(Xf) @ fcW + fcb          (fp64 acc)
// ---------------------------------------------------------------------------

static inline size_t ws_align(size_t x) { return (x + 255) & ~(size_t)255; }

// ---------------- trivial utility kernels ----------------

__global__ __launch_bounds__(256) void zero_i32(int* __restrict__ p, int n) {
    int i = blockIdx.x * 256 + threadIdx.x;
    if (i < n) p[i] = 0;
}

__global__ __launch_bounds__(256) void copy_i32(const int* __restrict__ a,
                                                int* __restrict__ b, int n) {
    int i = blockIdx.x * 256 + threadIdx.x;
    if (i < n) b[i] = a[i];
}

__global__ __launch_bounds__(256) void deg_kernel(const int* __restrict__ dst,
                                                  int* __restrict__ deg, int E) {
    int e = blockIdx.x * 256 + threadIdx.x;
    if (e < E) atomicAdd(&deg[dst[e]], 1);
}

__global__ __launch_bounds__(256) void dinv_kernel(const int* __restrict__ deg,
                                                   float* __restrict__ dinv, int n) {
    int i = blockIdx.x * 256 + threadIdx.x;
    if (i < n) dinv[i] = (float)(1.0 / sqrt((double)(deg[i] + 1)));
}

// ---------------- exclusive scan of deg -> rowptr (chunks of 1024) ----------

__global__ __launch_bounds__(256) void scan_bsum(const int* __restrict__ deg,
                                                 int* __restrict__ bsum, int N) {
    __shared__ int sd[256];
    int b = blockIdx.x, t = threadIdx.x;
    int base = b * 1024 + t * 4;
    int s = 0;
#pragma unroll
    for (int i = 0; i < 4; ++i) { int idx = base + i; if (idx < N) s += deg[idx]; }
    sd[t] = s; __syncthreads();
    for (int off = 128; off > 0; off >>= 1) {
        if (t < off) sd[t] += sd[t + off];
        __syncthreads();
    }
    if (t == 0) bsum[b] = sd[0];
}

__global__ void scan_boff(const int* __restrict__ bsum, int* __restrict__ boff,
                          int* __restrict__ rowptr_last, int G) {
    if (threadIdx.x == 0 && blockIdx.x == 0) {
        int acc = 0;
        for (int b = 0; b < G; ++b) { boff[b] = acc; acc += bsum[b]; }
        rowptr_last[0] = acc;   // rowptr[N] = E
    }
}

__global__ __launch_bounds__(256) void scan_final(const int* __restrict__ deg,
                                                  const int* __restrict__ boff,
                                                  int* __restrict__ rowptr, int N) {
    __shared__ int sd[256];
    int b = blockIdx.x, t = threadIdx.x;
    int base = b * 1024 + t * 4;
    int v[4]; int s = 0;
#pragma unroll
    for (int i = 0; i < 4; ++i) {
        v[i] = (base + i < N) ? deg[base + i] : 0;
        s += v[i];
    }
    sd[t] = s; __syncthreads();
    // inclusive Hillis-Steele scan over thread sums
    for (int off = 1; off < 256; off <<= 1) {
        int y = (t >= off) ? sd[t - off] : 0;
        __syncthreads();
        sd[t] += y;
        __syncthreads();
    }
    int pre = boff[b] + sd[t] - s;   // exclusive prefix for this thread
#pragma unroll
    for (int i = 0; i < 4; ++i) {
        if (base + i < N) rowptr[base + i] = pre;
        pre += v[i];
    }
}

// ---------------- CSR fill: slot per (dst) via cursor ------------------------

__global__ __launch_bounds__(256) void fill_csr(const int* __restrict__ src,
                                                const int* __restrict__ dst,
                                                const float* __restrict__ dinv,
                                                int* __restrict__ cursor,
                                                int* __restrict__ csr_src,
                                                float* __restrict__ csr_w, int E) {
    int e = blockIdx.x * 256 + threadIdx.x;
    if (e >= E) return;
    int s = src[e], d = dst[e];
    int slot = atomicAdd(&cursor[d], 1);
    csr_src[slot] = s;
    csr_w[slot] = dinv[s] * dinv[d];   // same fp32 rounding as reference norm
}

// ---------------- GEMM: H[N,128] = op(A)[N,128] @ W[128,128] (+ rootW2[batch])
// 32 rows/block, 256 threads, thread computes 4 rows x 4 cols, fp64 accum.

#define DSTEP(AC, AV, BV)                                   \
    AC[0] = fma((double)(AV), (double)(BV).x, AC[0]);       \
    AC[1] = fma((double)(AV), (double)(BV).y, AC[1]);       \
    AC[2] = fma((double)(AV), (double)(BV).z, AC[2]);       \
    AC[3] = fma((double)(AV), (double)(BV).w, AC[3]);

template <bool RELU_A, bool ADD_ROOT>
__global__ __launch_bounds__(256) void gemm_kernel(const float* __restrict__ A,
                                                   const float* __restrict__ W,
                                                   const float* __restrict__ rootW2,
                                                   const int* __restrict__ batch,
                                                   float* __restrict__ H, int N) {
    __shared__ float Ws[64 * 128];   // one K-half of W (32 KB)
    __shared__ float xs[32][132];

    const int t = threadIdx.x;
    const int row0 = blockIdx.x * 32;

    {   // stage A tile [32][128]
        int r = t >> 5, c4 = t & 31;
#pragma unroll
        for (int p = 0; p < 4; ++p) {
            int rr = r + p * 8;
            int grow = row0 + rr;
            float4 v = make_float4(0.f, 0.f, 0.f, 0.f);
            if (grow < N) v = *(const float4*)&A[(size_t)grow * 128 + c4 * 4];
            if (RELU_A) {
                v.x = fmaxf(v.x, 0.f); v.y = fmaxf(v.y, 0.f);
                v.z = fmaxf(v.z, 0.f); v.w = fmaxf(v.w, 0.f);
            }
            *(float4*)&xs[rr][c4 * 4] = v;
        }
    }

    const int rb = (t >> 5) * 4;
    const int cb = (t & 31) * 4;
    double acc[4][4];
#pragma unroll
    for (int i = 0; i < 4; ++i)
#pragma unroll
        for (int j = 0; j < 4; ++j) acc[i][j] = 0.0;

#pragma unroll
    for (int half = 0; half < 2; ++half) {
        __syncthreads();
        {   // stage 64 rows of W
            const float4* Wg = (const float4*)(W + (size_t)half * 64 * 128);
            float4* Wl = (float4*)Ws;
#pragma unroll
            for (int i = 0; i < 8; ++i) Wl[t + i * 256] = Wg[t + i * 256];
        }
        __syncthreads();

#pragma unroll
        for (int k4 = 0; k4 < 16; ++k4) {
            const int k = k4 * 4;
            const int kk = half * 64 + k;
            float4 a0 = *(const float4*)&xs[rb + 0][kk];
            float4 a1 = *(const float4*)&xs[rb + 1][kk];
            float4 a2 = *(const float4*)&xs[rb + 2][kk];
            float4 a3 = *(const float4*)&xs[rb + 3][kk];
            const float* wp = &Ws[(size_t)k * 128 + cb];
            float4 b0 = *(const float4*)&wp[0];
            float4 b1 = *(const float4*)&wp[128];
            float4 b2 = *(const float4*)&wp[256];
            float4 b3 = *(const float4*)&wp[384];
            DSTEP(acc[0], a0.x, b0); DSTEP(acc[0], a0.y, b1); DSTEP(acc[0], a0.z, b2); DSTEP(acc[0], a0.w, b3);
            DSTEP(acc[1], a1.x, b0); DSTEP(acc[1], a1.y, b1); DSTEP(acc[1], a1.z, b2); DSTEP(acc[1], a1.w, b3);
            DSTEP(acc[2], a2.x, b0); DSTEP(acc[2], a2.y, b1); DSTEP(acc[2], a2.z, b2); DSTEP(acc[2], a2.w, b3);
            DSTEP(acc[3], a3.x, b0); DSTEP(acc[3], a3.y, b1); DSTEP(acc[3], a3.z, b2); DSTEP(acc[3], a3.w, b3);
        }
    }

#pragma unroll
    for (int i = 0; i < 4; ++i) {
        int grow = row0 + rb + i;
        if (grow < N) {
            double r0 = acc[i][0], r1 = acc[i][1], r2 = acc[i][2], r3 = acc[i][3];
            if (ADD_ROOT) {
                int g = batch[grow];
                float4 rv = *(const float4*)&rootW2[(size_t)g * 128 + cb];
                r0 += (double)rv.x; r1 += (double)rv.y; r2 += (double)rv.z; r3 += (double)rv.w;
            }
            float4 o = make_float4((float)r0, (float)r1, (float)r2, (float)r3);
            *(float4*)&H[(size_t)grow * 128 + cb] = o;
        }
    }
}

// ---------------- CSR gather: out[i] = bias + h[i]*dinv^2 + sum_in h[s]*w ----
// one 64-lane wave per node, float2 per lane, fp64 accumulators.

__global__ __launch_bounds__(256) void gather_kernel(const float* __restrict__ h,
                                                     const float* __restrict__ dinv,
                                                     const int* __restrict__ rowptr,
                                                     const int* __restrict__ csr_src,
                                                     const float* __restrict__ csr_w,
                                                     const float* __restrict__ bias,
                                                     float* __restrict__ out,
                                                     int N, int ldo) {
    int wid = blockIdx.x * 4 + (threadIdx.x >> 6);
    if (wid >= N) return;
    int lane = threadIdx.x & 63;
    int r0 = rowptr[wid], r1 = rowptr[wid + 1];
    float di = dinv[wid];
    double wself = (double)di * (double)di;
    float2 hv = *(const float2*)&h[(size_t)wid * 128 + lane * 2];
    double a0 = (double)bias[lane * 2]     + (double)hv.x * wself;
    double a1 = (double)bias[lane * 2 + 1] + (double)hv.y * wself;
    for (int j = r0; j < r1; ++j) {
        int s = csr_src[j];
        float w = csr_w[j];
        float2 v = *(const float2*)&h[(size_t)s * 128 + lane * 2];
        a0 = fma((double)v.x, (double)w, a0);
        a1 = fma((double)v.y, (double)w, a1);
    }
    out[(size_t)wid * ldo + lane * 2]     = (float)a0;
    out[(size_t)wid * ldo + lane * 2 + 1] = (float)a1;
}

// ---------------- rootW2[g,:] = relu(x[root_g,:]) @ W2[128:,:] --------------
__global__ __launch_bounds__(128) void rootw2_kernel(const float* __restrict__ x,
                                                     const float* __restrict__ W2,
                                                     const int* __restrict__ rootindex,
                                                     float* __restrict__ rootW2, int B) {
    __shared__ float xr[128];
    int g = blockIdx.x;
    int c = threadIdx.x;
    int r = rootindex[g];
    xr[c] = fmaxf(x[(size_t)r * 128 + c], 0.f);
    __syncthreads();
    double acc = 0.0;
#pragma unroll 4
    for (int k = 0; k < 128; ++k)
        acc = fma((double)xr[k], (double)W2[(size_t)(128 + k) * 128 + c], acc);
    rootW2[(size_t)g * 128 + c] = (float)acc;
}

// ---------------- finalize: relu first half in place; second half = nrep[root]
__global__ __launch_bounds__(256) void finalize_kernel(const float* __restrict__ nrep,
                                                       const int* __restrict__ batch,
                                                       const int* __restrict__ rootindex,
                                                       float* __restrict__ Xf, int N) {
    int tid = blockIdx.x * 256 + threadIdx.x;    // N*64 threads
    int i = tid >> 6;
    if (i >= N) return;
    int q = tid & 63;
    if (q < 32) {
        float4* p = (float4*)&Xf[(size_t)i * 256 + q * 4];
        float4 v = *p;
        v.x = fmaxf(v.x, 0.f); v.y = fmaxf(v.y, 0.f);
        v.z = fmaxf(v.z, 0.f); v.w = fmaxf(v.w, 0.f);
        *p = v;
    } else {
        int c4 = q - 32;
        int r = rootindex[batch[i]];
        *(float4*)&Xf[(size_t)i * 256 + 128 + c4 * 4] =
            *(const float4*)&nrep[(size_t)r * 128 + c4 * 4];
    }
}

// ---------------- segment bounds over sorted batch --------------------------
__global__ __launch_bounds__(256) void bounds_kernel(const int* __restrict__ batch,
                                                     int* __restrict__ start, int N, int B) {
    int g = blockIdx.x * 256 + threadIdx.x;
    if (g > B) return;
    int lo = 0, hi = N;
    while (lo < hi) {
        int mid = (lo + hi) >> 1;
        if (batch[mid] < g) lo = mid + 1; else hi = mid;
    }
    start[g] = lo;
}

// ---------------- mean pool + FC (fp64 accum) -------------------------------
__global__ __launch_bounds__(256) void pool_kernel(const float* __restrict__ Xf,
                                                   const int* __restrict__ start,
                                                   const float* __restrict__ fcW,
                                                   const float* __restrict__ fcb,
                                                   float* __restrict__ out, int B) {
    __shared__ float pld[256];
    int g = blockIdx.x;
    int c = threadIdx.x;
    int s0 = start[g], s1 = start[g + 1];
    double acc = 0.0;
    for (int r = s0; r < s1; ++r) acc += (double)Xf[(size_t)r * 256 + c];
    double cnt = (double)(s1 - s0);
    pld[c] = (float)(acc / (cnt > 0.0 ? cnt : 1.0));
    __syncthreads();
    if (c < 4) {
        double o = (double)fcb[c];
#pragma unroll 4
        for (int k = 0; k < 256; ++k) o = fma((double)pld[k], (double)fcW[k * 4 + c], o);
        out[(size_t)g * 4 + c] = (float)o;
    }
}

// ---------------------------------------------------------------------------

extern "C" void kernel_launch(void* const* d_in, const int* in_sizes, int n_in,
                              void* d_out, int out_size, void* d_ws, size_t ws_size,
                              hipStream_t stream) {
    const float* x        = (const float*)d_in[0];
    const int*   ei       = (const int*)d_in[1];
    const int*   batch    = (const int*)d_in[2];
    const int*   rootidx  = (const int*)d_in[3];
    const float* W1       = (const float*)d_in[4];
    const float* b1       = (const float*)d_in[5];
    const float* W2       = (const float*)d_in[6];
    const float* b2       = (const float*)d_in[7];
    const float* fcW      = (const float*)d_in[8];
    const float* fcb      = (const float*)d_in[9];

    const int N = in_sizes[0] / 128;
    const int E = in_sizes[1] / 2;
    const int B = in_sizes[3];
    const int G = (N + 1023) / 1024;   // scan chunks

    const int* src  = ei;
    const int* dstv = ei + E;

    // workspace carve-up
    char* p = (char*)d_ws;
    int*   deg     = (int*)p;   p += ws_align((size_t)N * 4);       // later reused as cursor
    float* dinv    = (float*)p; p += ws_align((size_t)N * 4);
    int*   rowptr  = (int*)p;   p += ws_align((size_t)(N + 1) * 4);
    int*   csr_src = (int*)p;   p += ws_align((size_t)E * 4);
    float* csr_w   = (float*)p; p += ws_align((size_t)E * 4);
    float* h       = (float*)p; p += ws_align((size_t)N * 128 * 4); // h1, then h2
    float* nrep    = (float*)p; p += ws_align((size_t)N * 128 * 4); // node_rep1
    float* rootW2  = (float*)p; p += ws_align((size_t)B * 128 * 4);
    int*   start   = (int*)p;   p += ws_align((size_t)(B + 1) * 4);
    int*   bsum    = (int*)p;   p += ws_align((size_t)G * 4);
    int*   boff    = (int*)p;   p += ws_align((size_t)G * 4);

    float* out = (float*)d_out;          // [B,4]
    float* Xf  = out + (size_t)B * 4;    // [N,256]

    // degrees + norm
    zero_i32<<<(N + 255) / 256, 256, 0, stream>>>(deg, N);
    deg_kernel<<<(E + 255) / 256, 256, 0, stream>>>(dstv, deg, E);
    dinv_kernel<<<(N + 255) / 256, 256, 0, stream>>>(deg, dinv, N);

    // CSR build: rowptr = exclusive_scan(deg), rowptr[N] = E
    scan_bsum<<<G, 256, 0, stream>>>(deg, bsum, N);
    scan_boff<<<1, 64, 0, stream>>>(bsum, boff, rowptr + N, G);
    scan_final<<<G, 256, 0, stream>>>(deg, boff, rowptr, N);
    // cursor (reuse deg buffer) and fill
    copy_i32<<<(N + 255) / 256, 256, 0, stream>>>(rowptr, deg, N);
    fill_csr<<<(E + 255) / 256, 256, 0, stream>>>(src, dstv, dinv, deg, csr_src, csr_w, E);

    // conv1
    gemm_kernel<false, false><<<(N + 31) / 32, 256, 0, stream>>>(x, W1, nullptr, nullptr, h, N);
    gather_kernel<<<(N + 3) / 4, 256, 0, stream>>>(h, dinv, rowptr, csr_src, csr_w, b1, nrep, N, 128);

    // conv2 (root half precomputed per graph)
    rootw2_kernel<<<B, 128, 0, stream>>>(x, W2, rootidx, rootW2, B);
    gemm_kernel<true, true><<<(N + 31) / 32, 256, 0, stream>>>(nrep, W2, rootW2, batch, h, N);
    gather_kernel<<<(N + 3) / 4, 256, 0, stream>>>(h, dinv, rowptr, csr_src, csr_w, b2, Xf, N, 256);

    // epilogue
    bounds_kernel<<<(B + 256) / 256, 256, 0, stream>>>(batch, start, N, B);
    finalize_kernel<<<(N * 64 + 255) / 256, 256, 0, stream>>>(nrep, batch, rootidx, Xf, N);
    pool_kernel<<<B, 256, 0, stream>>>(Xf, start, fcW, fcb, out, B);
}

// Round 10
// 3106.390 us; speedup vs baseline: 5.4200x; 5.4200x over previous
//
#include <hip/hip_runtime.h>

// ---------------------------------------------------------------------------
// BiGCN-style forward: 2x GCNConv + root-extend + mean-pool + FC
// N=100000 nodes, E=1e6 edges, 128 feats, 512 graphs.
//
// Precision ledger (R1/R5/R9 evidence):
//   - fp32 GEMM accumulation FAILS (R1,R9: absmax 2.34e-2 > 2.03e-2, identical)
//   - fp64 everywhere PASSES (R5: 3.9e-3) but fp64 acc[4][4] spills
//     (VGPR=256, 9.5 GB scratch traffic, 8 ms/GEMM).
//   - This version: grouped-fp32 products + fp64 accumulate in GEMM
//     (4-term fp32 dot per k4 step, added to double acc: ~1e-6 rel error,
//      32 fp64 adds per output instead of 128 fp64 FMAs -> no spill).
//   - gather/rootw2/pool: fp64 acc (as in passing R5).
//
//   deg[i]    = in-degree(i)                       (int atomics, exact)
//   dinv      = (float)(1/sqrt(deg+1))             (exact to fp32)
//   CSR by dst: rowptr (scan of deg), csr_src, csr_w = dinv[s]*dinv[d]
//   h1        = x @ W1                             (GEMM, fp64-grouped acc)
//   nrep[d]   = b1 + h1[d]*dinv^2 + sum_in h1[s]*w (fp64 gather per node)
//   rootW2[g] = relu(x[root_g]) @ W2[128:]         (fp64 acc)
//   h2        = relu(nrep) @ W2[:128] + rootW2[batch]  (GEMM, fp64-grouped acc)
//   Xf[:,:128]  = relu(b2 + gather(h2))            (fp64 gather, relu in finalize)
//   Xf[:,128:]  = nrep[root(batch)]
//   out       = mean-pool(Xf) @ fcW + fcb          (fp64 acc, tiny)
// ---------------------------------------------------------------------------

static inline size_t ws_align(size_t x) { return (x + 255) & ~(size_t)255; }

// 4-term grouped dot per output column: p_j = sum_{q=0..3} a[q]*bq_j, fp32.
__device__ inline float4 dot4(const float4 a, const float4 b0, const float4 b1,
                              const float4 b2, const float4 b3) {
    float4 p;
    p.x = fmaf(a.w, b3.x, fmaf(a.z, b2.x, fmaf(a.y, b1.x, a.x * b0.x)));
    p.y = fmaf(a.w, b3.y, fmaf(a.z, b2.y, fmaf(a.y, b1.y, a.x * b0.y)));
    p.z = fmaf(a.w, b3.z, fmaf(a.z, b2.z, fmaf(a.y, b1.z, a.x * b0.z)));
    p.w = fmaf(a.w, b3.w, fmaf(a.z, b2.w, fmaf(a.y, b1.w, a.x * b0.w)));
    return p;
}

// ---------------- trivial utility kernels ----------------

__global__ __launch_bounds__(256) void zero_i32(int* __restrict__ p, int n) {
    int i = blockIdx.x * 256 + threadIdx.x;
    if (i < n) p[i] = 0;
}

__global__ __launch_bounds__(256) void copy_i32(const int* __restrict__ a,
                                                int* __restrict__ b, int n) {
    int i = blockIdx.x * 256 + threadIdx.x;
    if (i < n) b[i] = a[i];
}

__global__ __launch_bounds__(256) void deg_kernel(const int* __restrict__ dst,
                                                  int* __restrict__ deg, int E) {
    int e = blockIdx.x * 256 + threadIdx.x;
    if (e < E) atomicAdd(&deg[dst[e]], 1);
}

__global__ __launch_bounds__(256) void dinv_kernel(const int* __restrict__ deg,
                                                   float* __restrict__ dinv, int n) {
    int i = blockIdx.x * 256 + threadIdx.x;
    if (i < n) dinv[i] = (float)(1.0 / sqrt((double)(deg[i] + 1)));
}

// ---------------- exclusive scan of deg -> rowptr (chunks of 1024) ----------

__global__ __launch_bounds__(256) void scan_bsum(const int* __restrict__ deg,
                                                 int* __restrict__ bsum, int N) {
    __shared__ int sd[256];
    int b = blockIdx.x, t = threadIdx.x;
    int base = b * 1024 + t * 4;
    int s = 0;
#pragma unroll
    for (int i = 0; i < 4; ++i) { int idx = base + i; if (idx < N) s += deg[idx]; }
    sd[t] = s; __syncthreads();
    for (int off = 128; off > 0; off >>= 1) {
        if (t < off) sd[t] += sd[t + off];
        __syncthreads();
    }
    if (t == 0) bsum[b] = sd[0];
}

__global__ void scan_boff(const int* __restrict__ bsum, int* __restrict__ boff,
                          int* __restrict__ rowptr_last, int G) {
    if (threadIdx.x == 0 && blockIdx.x == 0) {
        int acc = 0;
        for (int b = 0; b < G; ++b) { boff[b] = acc; acc += bsum[b]; }
        rowptr_last[0] = acc;   // rowptr[N] = E
    }
}

__global__ __launch_bounds__(256) void scan_final(const int* __restrict__ deg,
                                                  const int* __restrict__ boff,
                                                  int* __restrict__ rowptr, int N) {
    __shared__ int sd[256];
    int b = blockIdx.x, t = threadIdx.x;
    int base = b * 1024 + t * 4;
    int v[4]; int s = 0;
#pragma unroll
    for (int i = 0; i < 4; ++i) {
        v[i] = (base + i < N) ? deg[base + i] : 0;
        s += v[i];
    }
    sd[t] = s; __syncthreads();
    // inclusive Hillis-Steele scan over thread sums
    for (int off = 1; off < 256; off <<= 1) {
        int y = (t >= off) ? sd[t - off] : 0;
        __syncthreads();
        sd[t] += y;
        __syncthreads();
    }
    int pre = boff[b] + sd[t] - s;   // exclusive prefix for this thread
#pragma unroll
    for (int i = 0; i < 4; ++i) {
        if (base + i < N) rowptr[base + i] = pre;
        pre += v[i];
    }
}

// ---------------- CSR fill: slot per (dst) via cursor ------------------------

__global__ __launch_bounds__(256) void fill_csr(const int* __restrict__ src,
                                                const int* __restrict__ dst,
                                                const float* __restrict__ dinv,
                                                int* __restrict__ cursor,
                                                int* __restrict__ csr_src,
                                                float* __restrict__ csr_w, int E) {
    int e = blockIdx.x * 256 + threadIdx.x;
    if (e >= E) return;
    int s = src[e], d = dst[e];
    int slot = atomicAdd(&cursor[d], 1);
    csr_src[slot] = s;
    csr_w[slot] = dinv[s] * dinv[d];   // same fp32 rounding as reference norm
}

// ---------------- GEMM: H[N,128] = op(A)[N,128] @ W[128,128] (+ rootW2[batch])
// 32 rows/block, 256 threads, thread = 4 rows x 4 cols.
// Grouped precision: fp32 4-term partial dots, fp64 accumulation.

template <bool RELU_A, bool ADD_ROOT>
__global__ __launch_bounds__(256) void gemm_kernel(const float* __restrict__ A,
                                                   const float* __restrict__ W,
                                                   const float* __restrict__ rootW2,
                                                   const int* __restrict__ batch,
                                                   float* __restrict__ H, int N) {
    __shared__ float Ws[64 * 128];   // one K-half of W (32 KB)
    __shared__ float xs[32][132];

    const int t = threadIdx.x;
    const int row0 = blockIdx.x * 32;

    {   // stage A tile [32][128]
        int r = t >> 5, c4 = t & 31;
#pragma unroll
        for (int p = 0; p < 4; ++p) {
            int rr = r + p * 8;
            int grow = row0 + rr;
            float4 v = make_float4(0.f, 0.f, 0.f, 0.f);
            if (grow < N) v = *(const float4*)&A[(size_t)grow * 128 + c4 * 4];
            if (RELU_A) {
                v.x = fmaxf(v.x, 0.f); v.y = fmaxf(v.y, 0.f);
                v.z = fmaxf(v.z, 0.f); v.w = fmaxf(v.w, 0.f);
            }
            *(float4*)&xs[rr][c4 * 4] = v;
        }
    }

    const int rb = (t >> 5) * 4;
    const int cb = (t & 31) * 4;
    double acc[4][4];
#pragma unroll
    for (int i = 0; i < 4; ++i)
#pragma unroll
        for (int j = 0; j < 4; ++j) acc[i][j] = 0.0;

#pragma unroll
    for (int half = 0; half < 2; ++half) {
        __syncthreads();
        {   // stage 64 rows of W
            const float4* Wg = (const float4*)(W + (size_t)half * 64 * 128);
            float4* Wl = (float4*)Ws;
#pragma unroll
            for (int i = 0; i < 8; ++i) Wl[t + i * 256] = Wg[t + i * 256];
        }
        __syncthreads();

#pragma unroll
        for (int k4 = 0; k4 < 16; ++k4) {
            const int k = k4 * 4;
            const int kk = half * 64 + k;
            const float* wp = &Ws[(size_t)k * 128 + cb];
            float4 b0 = *(const float4*)&wp[0];
            float4 b1 = *(const float4*)&wp[128];
            float4 b2 = *(const float4*)&wp[256];
            float4 b3 = *(const float4*)&wp[384];
#pragma unroll
            for (int i = 0; i < 4; ++i) {
                float4 a = *(const float4*)&xs[rb + i][kk];
                float4 p = dot4(a, b0, b1, b2, b3);
                acc[i][0] += (double)p.x;
                acc[i][1] += (double)p.y;
                acc[i][2] += (double)p.z;
                acc[i][3] += (double)p.w;
            }
        }
    }

#pragma unroll
    for (int i = 0; i < 4; ++i) {
        int grow = row0 + rb + i;
        if (grow < N) {
            double r0 = acc[i][0], r1 = acc[i][1], r2 = acc[i][2], r3 = acc[i][3];
            if (ADD_ROOT) {
                int g = batch[grow];
                float4 rv = *(const float4*)&rootW2[(size_t)g * 128 + cb];
                r0 += (double)rv.x; r1 += (double)rv.y; r2 += (double)rv.z; r3 += (double)rv.w;
            }
            float4 o = make_float4((float)r0, (float)r1, (float)r2, (float)r3);
            *(float4*)&H[(size_t)grow * 128 + cb] = o;
        }
    }
}

// ---------------- CSR gather: out[i] = bias + h[i]*dinv^2 + sum_in h[s]*w ----
// one 64-lane wave per node, float2 per lane, fp64 accumulators.

__global__ __launch_bounds__(256) void gather_kernel(const float* __restrict__ h,
                                                     const float* __restrict__ dinv,
                                                     const int* __restrict__ rowptr,
                                                     const int* __restrict__ csr_src,
                                                     const float* __restrict__ csr_w,
                                                     const float* __restrict__ bias,
                                                     float* __restrict__ out,
                                                     int N, int ldo) {
    int wid = blockIdx.x * 4 + (threadIdx.x >> 6);
    if (wid >= N) return;
    int lane = threadIdx.x & 63;
    int r0 = rowptr[wid], r1 = rowptr[wid + 1];
    float di = dinv[wid];
    double wself = (double)di * (double)di;
    float2 hv = *(const float2*)&h[(size_t)wid * 128 + lane * 2];
    double a0 = (double)bias[lane * 2]     + (double)hv.x * wself;
    double a1 = (double)bias[lane * 2 + 1] + (double)hv.y * wself;
    for (int j = r0; j < r1; ++j) {
        int s = csr_src[j];
        float w = csr_w[j];
        float2 v = *(const float2*)&h[(size_t)s * 128 + lane * 2];
        a0 = fma((double)v.x, (double)w, a0);
        a1 = fma((double)v.y, (double)w, a1);
    }
    out[(size_t)wid * ldo + lane * 2]     = (float)a0;
    out[(size_t)wid * ldo + lane * 2 + 1] = (float)a1;
}

// ---------------- rootW2[g,:] = relu(x[root_g,:]) @ W2[128:,:] (fp64 acc) ----
__global__ __launch_bounds__(128) void rootw2_kernel(const float* __restrict__ x,
                                                     const float* __restrict__ W2,
                                                     const int* __restrict__ rootindex,
                                                     float* __restrict__ rootW2, int B) {
    __shared__ float xr[128];
    int g = blockIdx.x;
    int c = threadIdx.x;
    int r = rootindex[g];
    xr[c] = fmaxf(x[(size_t)r * 128 + c], 0.f);
    __syncthreads();
    double acc = 0.0;
#pragma unroll 4
    for (int k = 0; k < 128; ++k)
        acc = fma((double)xr[k], (double)W2[(size_t)(128 + k) * 128 + c], acc);
    rootW2[(size_t)g * 128 + c] = (float)acc;
}

// ---------------- finalize: relu first half in place; second half = nrep[root]
__global__ __launch_bounds__(256) void finalize_kernel(const float* __restrict__ nrep,
                                                       const int* __restrict__ batch,
                                                       const int* __restrict__ rootindex,
                                                       float* __restrict__ Xf, int N) {
    int tid = blockIdx.x * 256 + threadIdx.x;    // N*64 threads
    int i = tid >> 6;
    if (i >= N) return;
    int q = tid & 63;
    if (q < 32) {
        float4* p = (float4*)&Xf[(size_t)i * 256 + q * 4];
        float4 v = *p;
        v.x = fmaxf(v.x, 0.f); v.y = fmaxf(v.y, 0.f);
        v.z = fmaxf(v.z, 0.f); v.w = fmaxf(v.w, 0.f);
        *p = v;
    } else {
        int c4 = q - 32;
        int r = rootindex[batch[i]];
        *(float4*)&Xf[(size_t)i * 256 + 128 + c4 * 4] =
            *(const float4*)&nrep[(size_t)r * 128 + c4 * 4];
    }
}

// ---------------- segment bounds over sorted batch --------------------------
__global__ __launch_bounds__(256) void bounds_kernel(const int* __restrict__ batch,
                                                     int* __restrict__ start, int N, int B) {
    int g = blockIdx.x * 256 + threadIdx.x;
    if (g > B) return;
    int lo = 0, hi = N;
    while (lo < hi) {
        int mid = (lo + hi) >> 1;
        if (batch[mid] < g) lo = mid + 1; else hi = mid;
    }
    start[g] = lo;
}

// ---------------- mean pool + FC (fp64 accum, tiny) -------------------------
__global__ __launch_bounds__(256) void pool_kernel(const float* __restrict__ Xf,
                                                   const int* __restrict__ start,
                                                   const float* __restrict__ fcW,
                                                   const float* __restrict__ fcb,
                                                   float* __restrict__ out, int B) {
    __shared__ float pld[256];
    int g = blockIdx.x;
    int c = threadIdx.x;
    int s0 = start[g], s1 = start[g + 1];
    double acc = 0.0;
    for (int r = s0; r < s1; ++r) acc += (double)Xf[(size_t)r * 256 + c];
    double cnt = (double)(s1 - s0);
    pld[c] = (float)(acc / (cnt > 0.0 ? cnt : 1.0));
    __syncthreads();
    if (c < 4) {
        double o = (double)fcb[c];
#pragma unroll 4
        for (int k = 0; k < 256; ++k) o = fma((double)pld[k], (double)fcW[k * 4 + c], o);
        out[(size_t)g * 4 + c] = (float)o;
    }
}

// ---------------------------------------------------------------------------

extern "C" void kernel_launch(void* const* d_in, const int* in_sizes, int n_in,
                              void* d_out, int out_size, void* d_ws, size_t ws_size,
                              hipStream_t stream) {
    const float* x        = (const float*)d_in[0];
    const int*   ei       = (const int*)d_in[1];
    const int*   batch    = (const int*)d_in[2];
    const int*   rootidx  = (const int*)d_in[3];
    const float* W1       = (const float*)d_in[4];
    const float* b1       = (const float*)d_in[5];
    const float* W2       = (const float*)d_in[6];
    const float* b2       = (const float*)d_in[7];
    const float* fcW      = (const float*)d_in[8];
    const float* fcb      = (const float*)d_in[9];

    const int N = in_sizes[0] / 128;
    const int E = in_sizes[1] / 2;
    const int B = in_sizes[3];
    const int G = (N + 1023) / 1024;   // scan chunks

    const int* src  = ei;
    const int* dstv = ei + E;

    // workspace carve-up
    char* p = (char*)d_ws;
    int*   deg     = (int*)p;   p += ws_align((size_t)N * 4);       // later reused as cursor
    float* dinv    = (float*)p; p += ws_align((size_t)N * 4);
    int*   rowptr  = (int*)p;   p += ws_align((size_t)(N + 1) * 4);
    int*   csr_src = (int*)p;   p += ws_align((size_t)E * 4);
    float* csr_w   = (float*)p; p += ws_align((size_t)E * 4);
    float* h       = (float*)p; p += ws_align((size_t)N * 128 * 4); // h1, then h2
    float* nrep    = (float*)p; p += ws_align((size_t)N * 128 * 4); // node_rep1
    float* rootW2  = (float*)p; p += ws_align((size_t)B * 128 * 4);
    int*   start   = (int*)p;   p += ws_align((size_t)(B + 1) * 4);
    int*   bsum    = (int*)p;   p += ws_align((size_t)G * 4);
    int*   boff    = (int*)p;   p += ws_align((size_t)G * 4);

    float* out = (float*)d_out;          // [B,4]
    float* Xf  = out + (size_t)B * 4;    // [N,256]

    // degrees + norm
    zero_i32<<<(N + 255) / 256, 256, 0, stream>>>(deg, N);
    deg_kernel<<<(E + 255) / 256, 256, 0, stream>>>(dstv, deg, E);
    dinv_kernel<<<(N + 255) / 256, 256, 0, stream>>>(deg, dinv, N);

    // CSR build: rowptr = exclusive_scan(deg), rowptr[N] = E
    scan_bsum<<<G, 256, 0, stream>>>(deg, bsum, N);
    scan_boff<<<1, 64, 0, stream>>>(bsum, boff, rowptr + N, G);
    scan_final<<<G, 256, 0, stream>>>(deg, boff, rowptr, N);
    // cursor (reuse deg buffer) and fill
    copy_i32<<<(N + 255) / 256, 256, 0, stream>>>(rowptr, deg, N);
    fill_csr<<<(E + 255) / 256, 256, 0, stream>>>(src, dstv, dinv, deg, csr_src, csr_w, E);

    // conv1
    gemm_kernel<false, false><<<(N + 31) / 32, 256, 0, stream>>>(x, W1, nullptr, nullptr, h, N);
    gather_kernel<<<(N + 3) / 4, 256, 0, stream>>>(h, dinv, rowptr, csr_src, csr_w, b1, nrep, N, 128);

    // conv2 (root half precomputed per graph)
    rootw2_kernel<<<B, 128, 0, stream>>>(x, W2, rootidx, rootW2, B);
    gemm_kernel<true, true><<<(N + 31) / 32, 256, 0, stream>>>(nrep, W2, rootW2, batch, h, N);
    gather_kernel<<<(N + 3) / 4, 256, 0, stream>>>(h, dinv, rowptr, csr_src, csr_w, b2, Xf, N, 256);

    // epilogue
    bounds_kernel<<<(B + 256) / 256, 256, 0, stream>>>(batch, start, N, B);
    finalize_kernel<<<(N * 64 + 255) / 256, 256, 0, stream>>>(nrep, batch, rootidx, Xf, N);
    pool_kernel<<<B, 256, 0, stream>>>(Xf, start, fcW, fcb, out, B);
}

// Round 11
// 755.241 us; speedup vs baseline: 22.2931x; 4.1131x over previous
//
#include <hip/hip_runtime.h>

// ---------------------------------------------------------------------------
// BiGCN-style forward: 2x GCNConv + root-extend + mean-pool + FC
// N=100000 nodes, E=1e6 edges, 128 feats, 512 graphs.
//
// Precision ledger (R1/R5/R9/R10 evidence):
//   - fp32 GEMM accumulation FAILS (R1,R9: absmax 2.34e-2 > 2.03e-2, identical)
//   - fp64 acc PASSES (R5, R10: 3.9e-3 = storage floor)
//   - grouped fp32-products + fp64-add = full-fp64 quality (R10)
// Perf ledger:
//   - R5: fp64 FMA chain, acc[4][4] dbl -> VGPR 256, 9.5 GB spill, 8 ms/GEMM
//   - R10: grouped acc, same 4x4 tile + full unroll -> STILL VGPR 256,
//     3.9 GB spill, 1.31 ms/GEMM. Diagnosis: 32-reg acc + unbounded unroll
//     window (compiler hoists LDS frags) -> forced scratch.
//   - R11 (this): 16-row tile (2x4/thread, 16-reg acc), #pragma unroll 2,
//     __launch_bounds__(256,4) = 128-VGPR cap. Predict ~100 MB traffic,
//     ~100 us/GEMM.
//
//   deg[i]    = in-degree(i)                       (int atomics, exact)
//   dinv      = (float)(1/sqrt(deg+1))             (exact to fp32)
//   CSR by dst: rowptr (scan of deg), csr_src, csr_w = dinv[s]*dinv[d]
//   h1        = x @ W1                             (GEMM, grouped fp64 acc)
//   nrep[d]   = b1 + h1[d]*dinv^2 + sum_in h1[s]*w (fp64 gather per node)
//   rootW2[g] = relu(x[root_g]) @ W2[128:]         (fp64 acc)
//   h2        = relu(nrep) @ W2[:128] + rootW2[batch]  (GEMM, grouped fp64 acc)
//   Xf[:,:128]  = relu(b2 + gather(h2))            (fp64 gather, relu in finalize)
//   Xf[:,128:]  = nrep[root(batch)]
//   out       = mean-pool(Xf) @ fcW + fcb          (fp64 acc, tiny)
// ---------------------------------------------------------------------------

static inline size_t ws_align(size_t x) { return (x + 255) & ~(size_t)255; }

// 4-term grouped dot per output column: p_j = sum_{q=0..3} a[q]*bq_j, fp32.
__device__ inline float4 dot4(const float4 a, const float4 b0, const float4 b1,
                              const float4 b2, const float4 b3) {
    float4 p;
    p.x = fmaf(a.w, b3.x, fmaf(a.z, b2.x, fmaf(a.y, b1.x, a.x * b0.x)));
    p.y = fmaf(a.w, b3.y, fmaf(a.z, b2.y, fmaf(a.y, b1.y, a.x * b0.y)));
    p.z = fmaf(a.w, b3.z, fmaf(a.z, b2.z, fmaf(a.y, b1.z, a.x * b0.z)));
    p.w = fmaf(a.w, b3.w, fmaf(a.z, b2.w, fmaf(a.y, b1.w, a.x * b0.w)));
    return p;
}

// ---------------- trivial utility kernels ----------------

__global__ __launch_bounds__(256) void zero_i32(int* __restrict__ p, int n) {
    int i = blockIdx.x * 256 + threadIdx.x;
    if (i < n) p[i] = 0;
}

__global__ __launch_bounds__(256) void copy_i32(const int* __restrict__ a,
                                                int* __restrict__ b, int n) {
    int i = blockIdx.x * 256 + threadIdx.x;
    if (i < n) b[i] = a[i];
}

__global__ __launch_bounds__(256) void deg_kernel(const int* __restrict__ dst,
                                                  int* __restrict__ deg, int E) {
    int e = blockIdx.x * 256 + threadIdx.x;
    if (e < E) atomicAdd(&deg[dst[e]], 1);
}

__global__ __launch_bounds__(256) void dinv_kernel(const int* __restrict__ deg,
                                                   float* __restrict__ dinv, int n) {
    int i = blockIdx.x * 256 + threadIdx.x;
    if (i < n) dinv[i] = (float)(1.0 / sqrt((double)(deg[i] + 1)));
}

// ---------------- exclusive scan of deg -> rowptr (chunks of 1024) ----------

__global__ __launch_bounds__(256) void scan_bsum(const int* __restrict__ deg,
                                                 int* __restrict__ bsum, int N) {
    __shared__ int sd[256];
    int b = blockIdx.x, t = threadIdx.x;
    int base = b * 1024 + t * 4;
    int s = 0;
#pragma unroll
    for (int i = 0; i < 4; ++i) { int idx = base + i; if (idx < N) s += deg[idx]; }
    sd[t] = s; __syncthreads();
    for (int off = 128; off > 0; off >>= 1) {
        if (t < off) sd[t] += sd[t + off];
        __syncthreads();
    }
    if (t == 0) bsum[b] = sd[0];
}

__global__ void scan_boff(const int* __restrict__ bsum, int* __restrict__ boff,
                          int* __restrict__ rowptr_last, int G) {
    if (threadIdx.x == 0 && blockIdx.x == 0) {
        int acc = 0;
        for (int b = 0; b < G; ++b) { boff[b] = acc; acc += bsum[b]; }
        rowptr_last[0] = acc;   // rowptr[N] = E
    }
}

__global__ __launch_bounds__(256) void scan_final(const int* __restrict__ deg,
                                                  const int* __restrict__ boff,
                                                  int* __restrict__ rowptr, int N) {
    __shared__ int sd[256];
    int b = blockIdx.x, t = threadIdx.x;
    int base = b * 1024 + t * 4;
    int v[4]; int s = 0;
#pragma unroll
    for (int i = 0; i < 4; ++i) {
        v[i] = (base + i < N) ? deg[base + i] : 0;
        s += v[i];
    }
    sd[t] = s; __syncthreads();
    // inclusive Hillis-Steele scan over thread sums
    for (int off = 1; off < 256; off <<= 1) {
        int y = (t >= off) ? sd[t - off] : 0;
        __syncthreads();
        sd[t] += y;
        __syncthreads();
    }
    int pre = boff[b] + sd[t] - s;   // exclusive prefix for this thread
#pragma unroll
    for (int i = 0; i < 4; ++i) {
        if (base + i < N) rowptr[base + i] = pre;
        pre += v[i];
    }
}

// ---------------- CSR fill: slot per (dst) via cursor ------------------------

__global__ __launch_bounds__(256) void fill_csr(const int* __restrict__ src,
                                                const int* __restrict__ dst,
                                                const float* __restrict__ dinv,
                                                int* __restrict__ cursor,
                                                int* __restrict__ csr_src,
                                                float* __restrict__ csr_w, int E) {
    int e = blockIdx.x * 256 + threadIdx.x;
    if (e >= E) return;
    int s = src[e], d = dst[e];
    int slot = atomicAdd(&cursor[d], 1);
    csr_src[slot] = s;
    csr_w[slot] = dinv[s] * dinv[d];   // same fp32 rounding as reference norm
}

// ---------------- GEMM: H[N,128] = op(A)[N,128] @ W[128,128] (+ rootW2[batch])
// 16 rows/block, 256 threads, thread = 2 rows x 4 cols (8 outputs, 16-reg acc).
// Grouped precision: fp32 4-term partial dots, fp64 accumulation.
// __launch_bounds__(256,4): hard 128-VGPR cap (512 VGPR/SIMD / 4 waves).

template <bool RELU_A, bool ADD_ROOT>
__global__ __launch_bounds__(256, 4) void gemm_kernel(const float* __restrict__ A,
                                                      const float* __restrict__ W,
                                                      const float* __restrict__ rootW2,
                                                      const int* __restrict__ batch,
                                                      float* __restrict__ H, int N) {
    __shared__ float Ws[64 * 128];   // one K-half of W (32 KB)
    __shared__ float xs[16][132];    // 16-row A tile, padded

    const int t = threadIdx.x;
    const int row0 = blockIdx.x * 16;

    {   // stage A tile [16][128]: 2 float4 per thread
        int r = t >> 5, c4 = t & 31;
#pragma unroll
        for (int p = 0; p < 2; ++p) {
            int rr = r + p * 8;
            int grow = row0 + rr;
            float4 v = make_float4(0.f, 0.f, 0.f, 0.f);
            if (grow < N) v = *(const float4*)&A[(size_t)grow * 128 + c4 * 4];
            if (RELU_A) {
                v.x = fmaxf(v.x, 0.f); v.y = fmaxf(v.y, 0.f);
                v.z = fmaxf(v.z, 0.f); v.w = fmaxf(v.w, 0.f);
            }
            *(float4*)&xs[rr][c4 * 4] = v;
        }
    }

    const int rb = (t >> 5) * 2;   // row base 0..14
    const int cb = (t & 31) * 4;   // col base 0..124
    double acc[2][4];
#pragma unroll
    for (int i = 0; i < 2; ++i)
#pragma unroll
        for (int j = 0; j < 4; ++j) acc[i][j] = 0.0;

#pragma unroll
    for (int half = 0; half < 2; ++half) {
        __syncthreads();
        {   // stage 64 rows of W: 2048 float4 / 256 threads = 8 each
            const float4* Wg = (const float4*)(W + (size_t)half * 64 * 128);
            float4* Wl = (float4*)Ws;
#pragma unroll
            for (int i = 0; i < 8; ++i) Wl[t + i * 256] = Wg[t + i * 256];
        }
        __syncthreads();

#pragma unroll 2
        for (int k4 = 0; k4 < 16; ++k4) {
            const int k = k4 * 4;
            const int kk = half * 64 + k;
            const float* wp = &Ws[(size_t)k * 128 + cb];
            float4 b0 = *(const float4*)&wp[0];
            float4 b1 = *(const float4*)&wp[128];
            float4 b2 = *(const float4*)&wp[256];
            float4 b3 = *(const float4*)&wp[384];
#pragma unroll
            for (int i = 0; i < 2; ++i) {
                float4 a = *(const float4*)&xs[rb + i][kk];
                float4 p = dot4(a, b0, b1, b2, b3);
                acc[i][0] += (double)p.x;
                acc[i][1] += (double)p.y;
                acc[i][2] += (double)p.z;
                acc[i][3] += (double)p.w;
            }
        }
    }

#pragma unroll
    for (int i = 0; i < 2; ++i) {
        int grow = row0 + rb + i;
        if (grow < N) {
            double r0 = acc[i][0], r1 = acc[i][1], r2 = acc[i][2], r3 = acc[i][3];
            if (ADD_ROOT) {
                int g = batch[grow];
                float4 rv = *(const float4*)&rootW2[(size_t)g * 128 + cb];
                r0 += (double)rv.x; r1 += (double)rv.y; r2 += (double)rv.z; r3 += (double)rv.w;
            }
            float4 o = make_float4((float)r0, (float)r1, (float)r2, (float)r3);
            *(float4*)&H[(size_t)grow * 128 + cb] = o;
        }
    }
}

// ---------------- CSR gather: out[i] = bias + h[i]*dinv^2 + sum_in h[s]*w ----
// one 64-lane wave per node, float2 per lane, fp64 accumulators.

__global__ __launch_bounds__(256) void gather_kernel(const float* __restrict__ h,
                                                     const float* __restrict__ dinv,
                                                     const int* __restrict__ rowptr,
                                                     const int* __restrict__ csr_src,
                                                     const float* __restrict__ csr_w,
                                                     const float* __restrict__ bias,
                                                     float* __restrict__ out,
                                                     int N, int ldo) {
    int wid = blockIdx.x * 4 + (threadIdx.x >> 6);
    if (wid >= N) return;
    int lane = threadIdx.x & 63;
    int r0 = rowptr[wid], r1 = rowptr[wid + 1];
    float di = dinv[wid];
    double wself = (double)di * (double)di;
    float2 hv = *(const float2*)&h[(size_t)wid * 128 + lane * 2];
    double a0 = (double)bias[lane * 2]     + (double)hv.x * wself;
    double a1 = (double)bias[lane * 2 + 1] + (double)hv.y * wself;
    for (int j = r0; j < r1; ++j) {
        int s = csr_src[j];
        float w = csr_w[j];
        float2 v = *(const float2*)&h[(size_t)s * 128 + lane * 2];
        a0 = fma((double)v.x, (double)w, a0);
        a1 = fma((double)v.y, (double)w, a1);
    }
    out[(size_t)wid * ldo + lane * 2]     = (float)a0;
    out[(size_t)wid * ldo + lane * 2 + 1] = (float)a1;
}

// ---------------- rootW2[g,:] = relu(x[root_g,:]) @ W2[128:,:] (fp64 acc) ----
__global__ __launch_bounds__(128) void rootw2_kernel(const float* __restrict__ x,
                                                     const float* __restrict__ W2,
                                                     const int* __restrict__ rootindex,
                                                     float* __restrict__ rootW2, int B) {
    __shared__ float xr[128];
    int g = blockIdx.x;
    int c = threadIdx.x;
    int r = rootindex[g];
    xr[c] = fmaxf(x[(size_t)r * 128 + c], 0.f);
    __syncthreads();
    double acc = 0.0;
#pragma unroll 4
    for (int k = 0; k < 128; ++k)
        acc = fma((double)xr[k], (double)W2[(size_t)(128 + k) * 128 + c], acc);
    rootW2[(size_t)g * 128 + c] = (float)acc;
}

// ---------------- finalize: relu first half in place; second half = nrep[root]
__global__ __launch_bounds__(256) void finalize_kernel(const float* __restrict__ nrep,
                                                       const int* __restrict__ batch,
                                                       const int* __restrict__ rootindex,
                                                       float* __restrict__ Xf, int N) {
    int tid = blockIdx.x * 256 + threadIdx.x;    // N*64 threads
    int i = tid >> 6;
    if (i >= N) return;
    int q = tid & 63;
    if (q < 32) {
        float4* p = (float4*)&Xf[(size_t)i * 256 + q * 4];
        float4 v = *p;
        v.x = fmaxf(v.x, 0.f); v.y = fmaxf(v.y, 0.f);
        v.z = fmaxf(v.z, 0.f); v.w = fmaxf(v.w, 0.f);
        *p = v;
    } else {
        int c4 = q - 32;
        int r = rootindex[batch[i]];
        *(float4*)&Xf[(size_t)i * 256 + 128 + c4 * 4] =
            *(const float4*)&nrep[(size_t)r * 128 + c4 * 4];
    }
}

// ---------------- segment bounds over sorted batch --------------------------
__global__ __launch_bounds__(256) void bounds_kernel(const int* __restrict__ batch,
                                                     int* __restrict__ start, int N, int B) {
    int g = blockIdx.x * 256 + threadIdx.x;
    if (g > B) return;
    int lo = 0, hi = N;
    while (lo < hi) {
        int mid = (lo + hi) >> 1;
        if (batch[mid] < g) lo = mid + 1; else hi = mid;
    }
    start[g] = lo;
}

// ---------------- mean pool + FC (fp64 accum, tiny) -------------------------
__global__ __launch_bounds__(256) void pool_kernel(const float* __restrict__ Xf,
                                                   const int* __restrict__ start,
                                                   const float* __restrict__ fcW,
                                                   const float* __restrict__ fcb,
                                                   float* __restrict__ out, int B) {
    __shared__ float pld[256];
    int g = blockIdx.x;
    int c = threadIdx.x;
    int s0 = start[g], s1 = start[g + 1];
    double acc = 0.0;
    for (int r = s0; r < s1; ++r) acc += (double)Xf[(size_t)r * 256 + c];
    double cnt = (double)(s1 - s0);
    pld[c] = (float)(acc / (cnt > 0.0 ? cnt : 1.0));
    __syncthreads();
    if (c < 4) {
        double o = (double)fcb[c];
#pragma unroll 4
        for (int k = 0; k < 256; ++k) o = fma((double)pld[k], (double)fcW[k * 4 + c], o);
        out[(size_t)g * 4 + c] = (float)o;
    }
}

// ---------------------------------------------------------------------------

extern "C" void kernel_launch(void* const* d_in, const int* in_sizes, int n_in,
                              void* d_out, int out_size, void* d_ws, size_t ws_size,
                              hipStream_t stream) {
    const float* x        = (const float*)d_in[0];
    const int*   ei       = (const int*)d_in[1];
    const int*   batch    = (const int*)d_in[2];
    const int*   rootidx  = (const int*)d_in[3];
    const float* W1       = (const float*)d_in[4];
    const float* b1       = (const float*)d_in[5];
    const float* W2       = (const float*)d_in[6];
    const float* b2       = (const float*)d_in[7];
    const float* fcW      = (const float*)d_in[8];
    const float* fcb      = (const float*)d_in[9];

    const int N = in_sizes[0] / 128;
    const int E = in_sizes[1] / 2;
    const int B = in_sizes[3];
    const int G = (N + 1023) / 1024;   // scan chunks

    const int* src  = ei;
    const int* dstv = ei + E;

    // workspace carve-up
    char* p = (char*)d_ws;
    int*   deg     = (int*)p;   p += ws_align((size_t)N * 4);       // later reused as cursor
    float* dinv    = (float*)p; p += ws_align((size_t)N * 4);
    int*   rowptr  = (int*)p;   p += ws_align((size_t)(N + 1) * 4);
    int*   csr_src = (int*)p;   p += ws_align((size_t)E * 4);
    float* csr_w   = (float*)p; p += ws_align((size_t)E * 4);
    float* h       = (float*)p; p += ws_align((size_t)N * 128 * 4); // h1, then h2
    float* nrep    = (float*)p; p += ws_align((size_t)N * 128 * 4); // node_rep1
    float* rootW2  = (float*)p; p += ws_align((size_t)B * 128 * 4);
    int*   start   = (int*)p;   p += ws_align((size_t)(B + 1) * 4);
    int*   bsum    = (int*)p;   p += ws_align((size_t)G * 4);
    int*   boff    = (int*)p;   p += ws_align((size_t)G * 4);

    float* out = (float*)d_out;          // [B,4]
    float* Xf  = out + (size_t)B * 4;    // [N,256]

    // degrees + norm
    zero_i32<<<(N + 255) / 256, 256, 0, stream>>>(deg, N);
    deg_kernel<<<(E + 255) / 256, 256, 0, stream>>>(dstv, deg, E);
    dinv_kernel<<<(N + 255) / 256, 256, 0, stream>>>(deg, dinv, N);

    // CSR build: rowptr = exclusive_scan(deg), rowptr[N] = E
    scan_bsum<<<G, 256, 0, stream>>>(deg, bsum, N);
    scan_boff<<<1, 64, 0, stream>>>(bsum, boff, rowptr + N, G);
    scan_final<<<G, 256, 0, stream>>>(deg, boff, rowptr, N);
    // cursor (reuse deg buffer) and fill
    copy_i32<<<(N + 255) / 256, 256, 0, stream>>>(rowptr, deg, N);
    fill_csr<<<(E + 255) / 256, 256, 0, stream>>>(src, dstv, dinv, deg, csr_src, csr_w, E);

    // conv1
    gemm_kernel<false, false><<<(N + 15) / 16, 256, 0, stream>>>(x, W1, nullptr, nullptr, h, N);
    gather_kernel<<<(N + 3) / 4, 256, 0, stream>>>(h, dinv, rowptr, csr_src, csr_w, b1, nrep, N, 128);

    // conv2 (root half precomputed per graph)
    rootw2_kernel<<<B, 128, 0, stream>>>(x, W2, rootidx, rootW2, B);
    gemm_kernel<true, true><<<(N + 15) / 16, 256, 0, stream>>>(nrep, W2, rootW2, batch, h, N);
    gather_kernel<<<(N + 3) / 4, 256, 0, stream>>>(h, dinv, rowptr, csr_src, csr_w, b2, Xf, N, 256);

    // epilogue
    bounds_kernel<<<(B + 256) / 256, 256, 0, stream>>>(batch, start, N, B);
    finalize_kernel<<<(N * 64 + 255) / 256, 256, 0, stream>>>(nrep, batch, rootidx, Xf, N);
    pool_kernel<<<B, 256, 0, stream>>>(Xf, start, fcW, fcb, out, B);
}

// Round 13
// 690.919 us; speedup vs baseline: 24.3685x; 1.0931x over previous
//
#include <hip/hip_runtime.h>

// ---------------------------------------------------------------------------
// BiGCN-style forward: 2x GCNConv + root-extend + mean-pool + FC
// N=100000 nodes, E=1e6 edges, 128 feats, 512 graphs.
//
// Precision ledger (R1/R5/R9/R10/R11):
//   - fp32 GEMM accumulation FAILS (R1,R9: absmax 2.34e-2, identical twice)
//   - grouped fp32-products + fp64-add GEMM PASSES at fp64 quality (R10/R11: 3.9e-3)
// Perf ledger:
//   - R10: 4x4 tile + full unroll -> VGPR 256 spill, 1.31 ms/GEMM
//   - R11: 16-row tile, 2x4/thread, unroll 2, __launch_bounds__(256,4)
//     -> spill gone, GEMMs <117 us, total 755 us. Top: gather 117.5 us x2
//     (VALU 21%, HBM 34%, occ 71% -> serial dependent-load chain, MLP=1).
//   - R12 (this): gather 4-edge unroll -> 4 h-row loads in flight;
//     fp64 FMA order unchanged (bit-identical). Predict gather ~65-85 us.
//
//   deg[i]    = in-degree(i)                       (int atomics, exact)
//   dinv      = (float)(1/sqrt(deg+1))             (exact to fp32)
//   CSR by dst: rowptr (scan of deg), csr_src, csr_w = dinv[s]*dinv[d]
//   h1        = x @ W1                             (GEMM, grouped fp64 acc)
//   nrep[d]   = b1 + h1[d]*dinv^2 + sum_in h1[s]*w (fp64 gather per node)
//   rootW2[g] = relu(x[root_g]) @ W2[128:]         (fp64 acc)
//   h2        = relu(nrep) @ W2[:128] + rootW2[batch]  (GEMM, grouped fp64 acc)
//   Xf[:,:128]  = relu(b2 + gather(h2))            (fp64 gather, relu in finalize)
//   Xf[:,128:]  = nrep[root(batch)]
//   out       = mean-pool(Xf) @ fcW + fcb          (fp64 acc, tiny)
// ---------------------------------------------------------------------------

static inline size_t ws_align(size_t x) { return (x + 255) & ~(size_t)255; }

// 4-term grouped dot per output column: p_j = sum_{q=0..3} a[q]*bq_j, fp32.
__device__ inline float4 dot4(const float4 a, const float4 b0, const float4 b1,
                              const float4 b2, const float4 b3) {
    float4 p;
    p.x = fmaf(a.w, b3.x, fmaf(a.z, b2.x, fmaf(a.y, b1.x, a.x * b0.x)));
    p.y = fmaf(a.w, b3.y, fmaf(a.z, b2.y, fmaf(a.y, b1.y, a.x * b0.y)));
    p.z = fmaf(a.w, b3.z, fmaf(a.z, b2.z, fmaf(a.y, b1.z, a.x * b0.z)));
    p.w = fmaf(a.w, b3.w, fmaf(a.z, b2.w, fmaf(a.y, b1.w, a.x * b0.w)));
    return p;
}

// ---------------- trivial utility kernels ----------------

__global__ __launch_bounds__(256) void zero_i32(int* __restrict__ p, int n) {
    int i = blockIdx.x * 256 + threadIdx.x;
    if (i < n) p[i] = 0;
}

__global__ __launch_bounds__(256) void copy_i32(const int* __restrict__ a,
                                                int* __restrict__ b, int n) {
    int i = blockIdx.x * 256 + threadIdx.x;
    if (i < n) b[i] = a[i];
}

__global__ __launch_bounds__(256) void deg_kernel(const int* __restrict__ dst,
                                                  int* __restrict__ deg, int E) {
    int e = blockIdx.x * 256 + threadIdx.x;
    if (e < E) atomicAdd(&deg[dst[e]], 1);
}

__global__ __launch_bounds__(256) void dinv_kernel(const int* __restrict__ deg,
                                                   float* __restrict__ dinv, int n) {
    int i = blockIdx.x * 256 + threadIdx.x;
    if (i < n) dinv[i] = (float)(1.0 / sqrt((double)(deg[i] + 1)));
}

// ---------------- exclusive scan of deg -> rowptr (chunks of 1024) ----------

__global__ __launch_bounds__(256) void scan_bsum(const int* __restrict__ deg,
                                                 int* __restrict__ bsum, int N) {
    __shared__ int sd[256];
    int b = blockIdx.x, t = threadIdx.x;
    int base = b * 1024 + t * 4;
    int s = 0;
#pragma unroll
    for (int i = 0; i < 4; ++i) { int idx = base + i; if (idx < N) s += deg[idx]; }
    sd[t] = s; __syncthreads();
    for (int off = 128; off > 0; off >>= 1) {
        if (t < off) sd[t] += sd[t + off];
        __syncthreads();
    }
    if (t == 0) bsum[b] = sd[0];
}

__global__ void scan_boff(const int* __restrict__ bsum, int* __restrict__ boff,
                          int* __restrict__ rowptr_last, int G) {
    if (threadIdx.x == 0 && blockIdx.x == 0) {
        int acc = 0;
        for (int b = 0; b < G; ++b) { boff[b] = acc; acc += bsum[b]; }
        rowptr_last[0] = acc;   // rowptr[N] = E
    }
}

__global__ __launch_bounds__(256) void scan_final(const int* __restrict__ deg,
                                                  const int* __restrict__ boff,
                                                  int* __restrict__ rowptr, int N) {
    __shared__ int sd[256];
    int b = blockIdx.x, t = threadIdx.x;
    int base = b * 1024 + t * 4;
    int v[4]; int s = 0;
#pragma unroll
    for (int i = 0; i < 4; ++i) {
        v[i] = (base + i < N) ? deg[base + i] : 0;
        s += v[i];
    }
    sd[t] = s; __syncthreads();
    // inclusive Hillis-Steele scan over thread sums
    for (int off = 1; off < 256; off <<= 1) {
        int y = (t >= off) ? sd[t - off] : 0;
        __syncthreads();
        sd[t] += y;
        __syncthreads();
    }
    int pre = boff[b] + sd[t] - s;   // exclusive prefix for this thread
#pragma unroll
    for (int i = 0; i < 4; ++i) {
        if (base + i < N) rowptr[base + i] = pre;
        pre += v[i];
    }
}

// ---------------- CSR fill: slot per (dst) via cursor ------------------------

__global__ __launch_bounds__(256) void fill_csr(const int* __restrict__ src,
                                                const int* __restrict__ dst,
                                                const float* __restrict__ dinv,
                                                int* __restrict__ cursor,
                                                int* __restrict__ csr_src,
                                                float* __restrict__ csr_w, int E) {
    int e = blockIdx.x * 256 + threadIdx.x;
    if (e >= E) return;
    int s = src[e], d = dst[e];
    int slot = atomicAdd(&cursor[d], 1);
    csr_src[slot] = s;
    csr_w[slot] = dinv[s] * dinv[d];   // same fp32 rounding as reference norm
}

// ---------------- GEMM: H[N,128] = op(A)[N,128] @ W[128,128] (+ rootW2[batch])
// 16 rows/block, 256 threads, thread = 2 rows x 4 cols (8 outputs, 16-reg acc).
// Grouped precision: fp32 4-term partial dots, fp64 accumulation.
// __launch_bounds__(256,4): hard 128-VGPR cap (512 VGPR/SIMD / 4 waves).

template <bool RELU_A, bool ADD_ROOT>
__global__ __launch_bounds__(256, 4) void gemm_kernel(const float* __restrict__ A,
                                                      const float* __restrict__ W,
                                                      const float* __restrict__ rootW2,
                                                      const int* __restrict__ batch,
                                                      float* __restrict__ H, int N) {
    __shared__ float Ws[64 * 128];   // one K-half of W (32 KB)
    __shared__ float xs[16][132];    // 16-row A tile, padded

    const int t = threadIdx.x;
    const int row0 = blockIdx.x * 16;

    {   // stage A tile [16][128]: 2 float4 per thread
        int r = t >> 5, c4 = t & 31;
#pragma unroll
        for (int p = 0; p < 2; ++p) {
            int rr = r + p * 8;
            int grow = row0 + rr;
            float4 v = make_float4(0.f, 0.f, 0.f, 0.f);
            if (grow < N) v = *(const float4*)&A[(size_t)grow * 128 + c4 * 4];
            if (RELU_A) {
                v.x = fmaxf(v.x, 0.f); v.y = fmaxf(v.y, 0.f);
                v.z = fmaxf(v.z, 0.f); v.w = fmaxf(v.w, 0.f);
            }
            *(float4*)&xs[rr][c4 * 4] = v;
        }
    }

    const int rb = (t >> 5) * 2;   // row base 0..14
    const int cb = (t & 31) * 4;   // col base 0..124
    double acc[2][4];
#pragma unroll
    for (int i = 0; i < 2; ++i)
#pragma unroll
        for (int j = 0; j < 4; ++j) acc[i][j] = 0.0;

#pragma unroll
    for (int half = 0; half < 2; ++half) {
        __syncthreads();
        {   // stage 64 rows of W: 2048 float4 / 256 threads = 8 each
            const float4* Wg = (const float4*)(W + (size_t)half * 64 * 128);
            float4* Wl = (float4*)Ws;
#pragma unroll
            for (int i = 0; i < 8; ++i) Wl[t + i * 256] = Wg[t + i * 256];
        }
        __syncthreads();

#pragma unroll 2
        for (int k4 = 0; k4 < 16; ++k4) {
            const int k = k4 * 4;
            const int kk = half * 64 + k;
            const float* wp = &Ws[(size_t)k * 128 + cb];
            float4 b0 = *(const float4*)&wp[0];
            float4 b1 = *(const float4*)&wp[128];
            float4 b2 = *(const float4*)&wp[256];
            float4 b3 = *(const float4*)&wp[384];
#pragma unroll
            for (int i = 0; i < 2; ++i) {
                float4 a = *(const float4*)&xs[rb + i][kk];
                float4 p = dot4(a, b0, b1, b2, b3);
                acc[i][0] += (double)p.x;
                acc[i][1] += (double)p.y;
                acc[i][2] += (double)p.z;
                acc[i][3] += (double)p.w;
            }
        }
    }

#pragma unroll
    for (int i = 0; i < 2; ++i) {
        int grow = row0 + rb + i;
        if (grow < N) {
            double r0 = acc[i][0], r1 = acc[i][1], r2 = acc[i][2], r3 = acc[i][3];
            if (ADD_ROOT) {
                int g = batch[grow];
                float4 rv = *(const float4*)&rootW2[(size_t)g * 128 + cb];
                r0 += (double)rv.x; r1 += (double)rv.y; r2 += (double)rv.z; r3 += (double)rv.w;
            }
            float4 o = make_float4((float)r0, (float)r1, (float)r2, (float)r3);
            *(float4*)&H[(size_t)grow * 128 + cb] = o;
        }
    }
}

// ---------------- CSR gather: out[i] = bias + h[i]*dinv^2 + sum_in h[s]*w ----
// one 64-lane wave per node, float2 per lane, fp64 accumulators.
// R12: 4-edge unroll -> 4 independent h-row loads in flight (MLP fix).
// FMA application order is IDENTICAL to the serial loop (bit-exact result).

__global__ __launch_bounds__(256) void gather_kernel(const float* __restrict__ h,
                                                     const float* __restrict__ dinv,
                                                     const int* __restrict__ rowptr,
                                                     const int* __restrict__ csr_src,
                                                     const float* __restrict__ csr_w,
                                                     const float* __restrict__ bias,
                                                     float* __restrict__ out,
                                                     int N, int ldo) {
    int wid = blockIdx.x * 4 + (threadIdx.x >> 6);
    if (wid >= N) return;
    int lane = threadIdx.x & 63;
    int r0 = rowptr[wid], r1 = rowptr[wid + 1];
    float di = dinv[wid];
    double wself = (double)di * (double)di;
    float2 hv = *(const float2*)&h[(size_t)wid * 128 + lane * 2];
    double a0 = (double)bias[lane * 2]     + (double)hv.x * wself;
    double a1 = (double)bias[lane * 2 + 1] + (double)hv.y * wself;

    int j = r0;
    for (; j + 4 <= r1; j += 4) {
        int s0 = csr_src[j];
        int s1 = csr_src[j + 1];
        int s2 = csr_src[j + 2];
        int s3 = csr_src[j + 3];
        float w0 = csr_w[j];
        float w1 = csr_w[j + 1];
        float w2 = csr_w[j + 2];
        float w3 = csr_w[j + 3];
        float2 v0 = *(const float2*)&h[(size_t)s0 * 128 + lane * 2];
        float2 v1 = *(const float2*)&h[(size_t)s1 * 128 + lane * 2];
        float2 v2 = *(const float2*)&h[(size_t)s2 * 128 + lane * 2];
        float2 v3 = *(const float2*)&h[(size_t)s3 * 128 + lane * 2];
        a0 = fma((double)v0.x, (double)w0, a0);
        a1 = fma((double)v0.y, (double)w0, a1);
        a0 = fma((double)v1.x, (double)w1, a0);
        a1 = fma((double)v1.y, (double)w1, a1);
        a0 = fma((double)v2.x, (double)w2, a0);
        a1 = fma((double)v2.y, (double)w2, a1);
        a0 = fma((double)v3.x, (double)w3, a0);
        a1 = fma((double)v3.y, (double)w3, a1);
    }
    for (; j < r1; ++j) {
        int s = csr_src[j];
        float w = csr_w[j];
        float2 v = *(const float2*)&h[(size_t)s * 128 + lane * 2];
        a0 = fma((double)v.x, (double)w, a0);
        a1 = fma((double)v.y, (double)w, a1);
    }
    out[(size_t)wid * ldo + lane * 2]     = (float)a0;
    out[(size_t)wid * ldo + lane * 2 + 1] = (float)a1;
}

// ---------------- rootW2[g,:] = relu(x[root_g,:]) @ W2[128:,:] (fp64 acc) ----
__global__ __launch_bounds__(128) void rootw2_kernel(const float* __restrict__ x,
                                                     const float* __restrict__ W2,
                                                     const int* __restrict__ rootindex,
                                                     float* __restrict__ rootW2, int B) {
    __shared__ float xr[128];
    int g = blockIdx.x;
    int c = threadIdx.x;
    int r = rootindex[g];
    xr[c] = fmaxf(x[(size_t)r * 128 + c], 0.f);
    __syncthreads();
    double acc = 0.0;
#pragma unroll 4
    for (int k = 0; k < 128; ++k)
        acc = fma((double)xr[k], (double)W2[(size_t)(128 + k) * 128 + c], acc);
    rootW2[(size_t)g * 128 + c] = (float)acc;
}

// ---------------- finalize: relu first half in place; second half = nrep[root]
__global__ __launch_bounds__(256) void finalize_kernel(const float* __restrict__ nrep,
                                                       const int* __restrict__ batch,
                                                       const int* __restrict__ rootindex,
                                                       float* __restrict__ Xf, int N) {
    int tid = blockIdx.x * 256 + threadIdx.x;    // N*64 threads
    int i = tid >> 6;
    if (i >= N) return;
    int q = tid & 63;
    if (q < 32) {
        float4* p = (float4*)&Xf[(size_t)i * 256 + q * 4];
        float4 v = *p;
        v.x = fmaxf(v.x, 0.f); v.y = fmaxf(v.y, 0.f);
        v.z = fmaxf(v.z, 0.f); v.w = fmaxf(v.w, 0.f);
        *p = v;
    } else {
        int c4 = q - 32;
        int r = rootindex[batch[i]];
        *(float4*)&Xf[(size_t)i * 256 + 128 + c4 * 4] =
            *(const float4*)&nrep[(size_t)r * 128 + c4 * 4];
    }
}

// ---------------- segment bounds over sorted batch --------------------------
__global__ __launch_bounds__(256) void bounds_kernel(const int* __restrict__ batch,
                                                     int* __restrict__ start, int N, int B) {
    int g = blockIdx.x * 256 + threadIdx.x;
    if (g > B) return;
    int lo = 0, hi = N;
    while (lo < hi) {
        int mid = (lo + hi) >> 1;
        if (batch[mid] < g) lo = mid + 1; else hi = mid;
    }
    start[g] = lo;
}

// ---------------- mean pool + FC (fp64 accum, tiny) -------------------------
__global__ __launch_bounds__(256) void pool_kernel(const float* __restrict__ Xf,
                                                   const int* __restrict__ start,
                                                   const float* __restrict__ fcW,
                                                   const float* __restrict__ fcb,
                                                   float* __restrict__ out, int B) {
    __shared__ float pld[256];
    int g = blockIdx.x;
    int c = threadIdx.x;
    int s0 = start[g], s1 = start[g + 1];
    double acc = 0.0;
    for (int r = s0; r < s1; ++r) acc += (double)Xf[(size_t)r * 256 + c];
    double cnt = (double)(s1 - s0);
    pld[c] = (float)(acc / (cnt > 0.0 ? cnt : 1.0));
    __syncthreads();
    if (c < 4) {
        double o = (double)fcb[c];
#pragma unroll 4
        for (int k = 0; k < 256; ++k) o = fma((double)pld[k], (double)fcW[k * 4 + c], o);
        out[(size_t)g * 4 + c] = (float)o;
    }
}

// ---------------------------------------------------------------------------

extern "C" void kernel_launch(void* const* d_in, const int* in_sizes, int n_in,
                              void* d_out, int out_size, void* d_ws, size_t ws_size,
                              hipStream_t stream) {
    const float* x        = (const float*)d_in[0];
    const int*   ei       = (const int*)d_in[1];
    const int*   batch    = (const int*)d_in[2];
    const int*   rootidx  = (const int*)d_in[3];
    const float* W1       = (const float*)d_in[4];
    const float* b1       = (const float*)d_in[5];
    const float* W2       = (const float*)d_in[6];
    const float* b2       = (const float*)d_in[7];
    const float* fcW      = (const float*)d_in[8];
    const float* fcb      = (const float*)d_in[9];

    const int N = in_sizes[0] / 128;
    const int E = in_sizes[1] / 2;
    const int B = in_sizes[3];
    const int G = (N + 1023) / 1024;   // scan chunks

    const int* src  = ei;
    const int* dstv = ei + E;

    // workspace carve-up
    char* p = (char*)d_ws;
    int*   deg     = (int*)p;   p += ws_align((size_t)N * 4);       // later reused as cursor
    float* dinv    = (float*)p; p += ws_align((size_t)N * 4);
    int*   rowptr  = (int*)p;   p += ws_align((size_t)(N + 1) * 4);
    int*   csr_src = (int*)p;   p += ws_align((size_t)E * 4);
    float* csr_w   = (float*)p; p += ws_align((size_t)E * 4);
    float* h       = (float*)p; p += ws_align((size_t)N * 128 * 4); // h1, then h2
    float* nrep    = (float*)p; p += ws_align((size_t)N * 128 * 4); // node_rep1
    float* rootW2  = (float*)p; p += ws_align((size_t)B * 128 * 4);
    int*   start   = (int*)p;   p += ws_align((size_t)(B + 1) * 4);
    int*   bsum    = (int*)p;   p += ws_align((size_t)G * 4);
    int*   boff    = (int*)p;   p += ws_align((size_t)G * 4);

    float* out = (float*)d_out;          // [B,4]
    float* Xf  = out + (size_t)B * 4;    // [N,256]

    // degrees + norm
    zero_i32<<<(N + 255) / 256, 256, 0, stream>>>(deg, N);
    deg_kernel<<<(E + 255) / 256, 256, 0, stream>>>(dstv, deg, E);
    dinv_kernel<<<(N + 255) / 256, 256, 0, stream>>>(deg, dinv, N);

    // CSR build: rowptr = exclusive_scan(deg), rowptr[N] = E
    scan_bsum<<<G, 256, 0, stream>>>(deg, bsum, N);
    scan_boff<<<1, 64, 0, stream>>>(bsum, boff, rowptr + N, G);
    scan_final<<<G, 256, 0, stream>>>(deg, boff, rowptr, N);
    // cursor (reuse deg buffer) and fill
    copy_i32<<<(N + 255) / 256, 256, 0, stream>>>(rowptr, deg, N);
    fill_csr<<<(E + 255) / 256, 256, 0, stream>>>(src, dstv, dinv, deg, csr_src, csr_w, E);

    // conv1
    gemm_kernel<false, false><<<(N + 15) / 16, 256, 0, stream>>>(x, W1, nullptr, nullptr, h, N);
    gather_kernel<<<(N + 3) / 4, 256, 0, stream>>>(h, dinv, rowptr, csr_src, csr_w, b1, nrep, N, 128);

    // conv2 (root half precomputed per graph)
    rootw2_kernel<<<B, 128, 0, stream>>>(x, W2, rootidx, rootW2, B);
    gemm_kernel<true, true><<<(N + 15) / 16, 256, 0, stream>>>(nrep, W2, rootW2, batch, h, N);
    gather_kernel<<<(N + 3) / 4, 256, 0, stream>>>(h, dinv, rowptr, csr_src, csr_w, b2, Xf, N, 256);

    // epilogue
    bounds_kernel<<<(B + 256) / 256, 256, 0, stream>>>(batch, start, N, B);
    finalize_kernel<<<(N * 64 + 255) / 256, 256, 0, stream>>>(nrep, batch, rootidx, Xf, N);
    pool_kernel<<<B, 256, 0, stream>>>(Xf, start, fcW, fcb, out, B);
}